// Round 6
// baseline (6313.387 us; speedup 1.0000x reference)
//
#include <hip/hip_runtime.h>
#include <stdint.h>

#define NB 64
#define NS 1024
#define ND 1024
#define NG 4096
#define CHUNK 128
#define NCHUNK 8

typedef __attribute__((ext_vector_type(4))) float f32x4;
typedef __attribute__((ext_vector_type(8))) short bf16x8;

__device__ __forceinline__ float bf2f(uint16_t u) {
  return __uint_as_float(((uint32_t)u) << 16);
}
__device__ __forceinline__ uint16_t f2bf(float f) {
  uint32_t x = __float_as_uint(f);
  return (uint16_t)((x + 0x7fffu + ((x >> 16) & 1u)) >> 16);
}
__device__ __forceinline__ float sigmoidf_(float x) {
  return 1.f / (1.f + __expf(-x));
}
__device__ __forceinline__ float tanhf_(float x) {
  return 1.f - 2.f / (__expf(x + x) + 1.f);
}
__device__ __forceinline__ void gload_lds16(const void* g, void* l) {
  __builtin_amdgcn_global_load_lds(
      (const __attribute__((address_space(1))) uint32_t*)g,
      (__attribute__((address_space(3))) uint32_t*)l, 16, 0, 0);
}

// ---------------- convert fp32 -> bf16 (weights only) ----------------
__global__ void k_cvt(const float* __restrict__ src, uint16_t* __restrict__ dst, int n4) {
  int stride = gridDim.x * blockDim.x;
  for (int i = blockIdx.x * blockDim.x + threadIdx.x; i < n4; i += stride) {
    float4 v = ((const float4*)src)[i];
    ushort4 o;
    o.x = f2bf(v.x); o.y = f2bf(v.y); o.z = f2bf(v.z); o.w = f2bf(v.w);
    ((ushort4*)dst)[i] = o;
  }
}

// ---------------- GEMM tile: [128 steps x 1024] x [1024 x 128] -> XP ----------------
__device__ __forceinline__ void gemm_tile(const float* __restrict__ A0,
                                          const uint16_t* __restrict__ Wx,
                                          uint16_t* __restrict__ XP,
                                          int b, int nb, int tid, char* lmem) {
  uint16_t* lAx = (uint16_t*)lmem;
  uint16_t* lBx = (uint16_t*)(lmem + 8192);
  const uint16_t* B0 = Wx + (size_t)(nb * 128) * ND;
  const int lane = tid & 63, wv = tid >> 6;
  const int m_off = (wv >> 1) << 6, n_off = (wv & 1) << 6;

  f32x4 acc[4][4] = {};
  for (int kb = 0; kb < ND / 32; ++kb) {
    const int k0 = kb * 32;
#pragma unroll
    for (int j = 0; j < 2; ++j) {
      int cid = j * 256 + tid;
      int row = cid >> 2, cc = cid & 3;
      int cs = cc ^ (row & 3);
      gload_lds16(B0 + (size_t)row * ND + k0 + cs * 8, (char*)lBx + cid * 16);
    }
#pragma unroll
    for (int j = 0; j < 2; ++j) {
      int cid = j * 256 + tid;
      int row = cid >> 2, cc = cid & 3;
      const float* ap = A0 + (size_t)row * ND + k0 + cc * 8;
      float4 u = *(const float4*)ap;
      float4 w = *(const float4*)(ap + 4);
      bf16x8 pk;
      pk[0] = (short)f2bf(u.x); pk[1] = (short)f2bf(u.y);
      pk[2] = (short)f2bf(u.z); pk[3] = (short)f2bf(u.w);
      pk[4] = (short)f2bf(w.x); pk[5] = (short)f2bf(w.y);
      pk[6] = (short)f2bf(w.z); pk[7] = (short)f2bf(w.w);
      int cs = cc ^ (row & 3);
      *(bf16x8*)((char*)lAx + row * 64 + cs * 16) = pk;
    }
    __syncthreads();
    bf16x8 af[4], bfr[4];
#pragma unroll
    for (int i = 0; i < 4; ++i) {
      int row = m_off + i * 16 + (lane & 15);
      int ch = (lane >> 4) ^ (row & 3);
      af[i] = *(const bf16x8*)((const char*)lAx + row * 64 + ch * 16);
      int rowb = n_off + i * 16 + (lane & 15);
      int chb = (lane >> 4) ^ (rowb & 3);
      bfr[i] = *(const bf16x8*)((const char*)lBx + rowb * 64 + chb * 16);
    }
#pragma unroll
    for (int i = 0; i < 4; ++i)
#pragma unroll
      for (int j2 = 0; j2 < 4; ++j2)
        acc[i][j2] = __builtin_amdgcn_mfma_f32_16x16x32_bf16(af[i], bfr[j2], acc[i][j2], 0, 0, 0);
    __syncthreads();
  }
#pragma unroll
  for (int i = 0; i < 4; ++i)
#pragma unroll
    for (int j2 = 0; j2 < 4; ++j2)
#pragma unroll
      for (int r = 0; r < 4; ++r) {
        int m = m_off + i * 16 + ((lane >> 4) << 2) + r;
        int n = nb * 128 + n_off + j2 * 16 + (lane & 15);
        XP[((size_t)(m * NB + b)) * NG + n] = f2bf(acc[i][j2][r]);
      }
}

// ---------------- fused dispatch ----------------
// bids 0..63: paired-group LSTM (pair p = bid>>5, d-slice g_d = bid&31).
// bids 64..255: x_proj GEMM for chunk+1. Prologue (chunk<0): all bids GEMM chunk 0.
__global__ __launch_bounds__(512, 2) void k_fused(
    const float* __restrict__ emb,
    const uint16_t* __restrict__ Wx,
    const uint16_t* __restrict__ Wh,
    uint16_t* __restrict__ xpA, uint16_t* __restrict__ xpB,
    const float* __restrict__ b_i, const float* __restrict__ b_f,
    const float* __restrict__ b_g, const float* __restrict__ b_o,
    uint16_t* __restrict__ hring,        // [NB][NS][ND] bf16, write-once per (b,t)
    float* __restrict__ cbuf,
    uint32_t* __restrict__ flags,        // [NS][4][32] slots, 16B stride
    float* __restrict__ out, int chunk) {
  __shared__ char smem[65552];           // lstm: 2x32KB lH + sync; gemm: 2x16KB
  const int bid = blockIdx.x;
  const int tid = threadIdx.x;

  if (chunk < 0 || bid >= 64) {
    const int gc = (chunk < 0) ? 0 : chunk + 1;
    if (gc >= NCHUNK) return;
    uint16_t* XP = (gc & 1) ? xpB : xpA;
    const int nw = (chunk < 0) ? 512 : 384;
    const int widx = ((chunk < 0) ? bid : bid - 64) * 2 + (tid >> 8);
    const int t256 = tid & 255;
    char* lmem = smem + ((tid >> 8) << 14);
    const int t0g = gc * CHUNK;
    for (int job = widx; job < 64 * 32; job += nw) {
      int b = job & 63, nb = job >> 6;
      gemm_tile(emb + ((size_t)b * NS + t0g) * ND, Wx, XP, b, nb, t256, lmem);
    }
    return;
  }

  // ---------------- LSTM role ----------------
  uint16_t* lHA = (uint16_t*)smem;                 // 32 KB, group A h-stage
  uint16_t* lHB = (uint16_t*)(smem + 32768);       // 32 KB, group B h-stage
  int* lds_sync = (int*)(smem + 65536);

  const int lane = tid & 63, wv = tid >> 6;
  const int p = bid >> 5;                 // pair 0/1
  const int g_d = bid & 31;               // d-slice
  const int grpA = p * 2, grpB = p * 2 + 1;
  const uint16_t* XP = (chunk & 1) ? xpB : xpA;
  const int t0 = chunk * CHUNK;

  const int q = lane >> 4, nl = lane & 15;
  const int g = nl & 3;                   // gate id (0=i,1=f,2=g,3=o)
  const int d_loc = wv * 4 + (nl >> 2);   // 0..31
  const int dg = g_d * 32 + d_loc;        // global d
  const int bA0 = grpA * 16 + q * 4;
  const int bB0 = grpB * 16 + q * 4;

  const uint16_t* wrow = Wh + ((size_t)g * ND + dg) * ND;
  bf16x8 wfr[32];
#pragma unroll
  for (int kk = 0; kk < 32; ++kk)
    wfr[kk] = *(const bf16x8*)(wrow + kk * 32 + q * 8);

  const float* bptr = (g == 0) ? b_i : (g == 1) ? b_f : (g == 2) ? b_g : b_o;
  const float Bv = bptr[dg];

  float cA[4], cB[4];
  if (t0 == 0) {
#pragma unroll
    for (int r = 0; r < 4; ++r) { cA[r] = 0.f; cB[r] = 0.f; }
  } else {
#pragma unroll
    for (int r = 0; r < 4; ++r) {
      cA[r] = cbuf[(size_t)(bA0 + r) * ND + dg];
      cB[r] = cbuf[(size_t)(bB0 + r) * ND + dg];
    }
  }

  auto do_stage = [&](int grp, int ts, uint16_t* lH, int token) {
    if (wv == 0) {
      const uint32_t* fl = flags + ((((size_t)ts * 4 + grp) << 5) + (lane & 31)) * 4;
      uint32_t v;
      do {
        v = __hip_atomic_load(fl, __ATOMIC_RELAXED, __HIP_MEMORY_SCOPE_AGENT);
      } while (__any(v == 0));
      if (lane == 0)
        __hip_atomic_store(lds_sync, token, __ATOMIC_RELAXED, __HIP_MEMORY_SCOPE_WORKGROUP);
    } else {
      while (__hip_atomic_load(lds_sync, __ATOMIC_RELAXED, __HIP_MEMORY_SCOPE_WORKGROUP) < token) {}
    }
    const int g16 = grp << 4;
#pragma unroll
    for (int j = 0; j < 4; ++j) {
      int ch = wv * 64 + j * 512 + lane;
      int row = ch >> 7, c = ch & 127;
      const uint16_t* src = hring + ((size_t)(g16 + row) * NS + ts) * ND + ((c ^ (row & 7)) << 3);
      gload_lds16(src, (char*)lH + ch * 16);
    }
  };

  auto do_mfma = [&](const uint16_t* lH, f32x4& A0, f32x4& A1, f32x4& A2, f32x4& A3) {
#pragma unroll
    for (int kk = 0; kk < 32; ++kk) {
      int cs = (kk * 4 + q) ^ (nl & 7);
      bf16x8 af = *(const bf16x8*)((const char*)lH + nl * 2048 + cs * 16);
      if ((kk & 3) == 0)      A0 = __builtin_amdgcn_mfma_f32_16x16x32_bf16(af, wfr[kk], A0, 0, 0, 0);
      else if ((kk & 3) == 1) A1 = __builtin_amdgcn_mfma_f32_16x16x32_bf16(af, wfr[kk], A1, 0, 0, 0);
      else if ((kk & 3) == 2) A2 = __builtin_amdgcn_mfma_f32_16x16x32_bf16(af, wfr[kk], A2, 0, 0, 0);
      else                    A3 = __builtin_amdgcn_mfma_f32_16x16x32_bf16(af, wfr[kk], A3, 0, 0, 0);
    }
  };

  auto do_gates = [&](f32x4& A0, f32x4& A1, f32x4& A2, f32x4& A3,
                      uint16_t X0, uint16_t X1, uint16_t X2, uint16_t X3,
                      float* cc, int b0, int t) {
    float xr[4] = { bf2f(X0), bf2f(X1), bf2f(X2), bf2f(X3) };
    float hval = 0.f;
#pragma unroll
    for (int r = 0; r < 4; ++r) {
      float v = A0[r] + A1[r] + A2[r] + A3[r] + xr[r] + Bv;
      float act = (g == 2) ? tanhf_(v) : sigmoidf_(v);
      float s1 = __shfl_xor(act, 1);
      float pe = (g & 1) ? s1 : act;
      float po = (g & 1) ? act : s1;
      float qe = __shfl_xor(pe, 2);
      float qo = __shfl_xor(po, 2);
      float gi = (g & 2) ? qe : pe;
      float gf = (g & 2) ? qo : po;
      float gg2 = (g & 2) ? pe : qe;
      float go = (g & 2) ? po : qo;
      float cn = __builtin_fmaf(gf, cc[r], gi * gg2);
      cc[r] = cn;
      float h = go * tanhf_(cn);
      if (r == g) hval = h;
    }
    int hv = (int)f2bf(hval);
    int pp = __shfl_xor(hv, 4);
    uint32_t v32 = ((nl >> 2) & 1) ? ((uint32_t)pp | ((uint32_t)hv << 16))
                                   : ((uint32_t)hv | ((uint32_t)pp << 16));
    uint32_t hi2 = (uint32_t)__shfl_xor((int)v32, 8);
    if (nl < 4) {
      uint64_t val = (uint64_t)v32 | ((uint64_t)hi2 << 32);
      uint16_t* dst = hring + ((size_t)(b0 + nl) * NS + t) * ND + dg;  // dg == colbase for nl<4
      __hip_atomic_store((uint64_t*)dst, val, __ATOMIC_RELAXED, __HIP_MEMORY_SCOPE_AGENT);
    }
    if (t == NS - 1) out[(size_t)(b0 + g) * ND + dg] = hval;
  };

  int token = 0;
  if (tid == 0)
    __hip_atomic_store(lds_sync, 0, __ATOMIC_RELAXED, __HIP_MEMORY_SCOPE_WORKGROUP);
  __syncthreads();
  if (t0 > 0) { token = 1; do_stage(grpA, t0 - 1, lHA, token); }
  __syncthreads();   // drains prologue gloads; lHA ready for A(t0)

  // XP for A(t0)
  const uint16_t* xa0p = XP + ((size_t)bA0) * NG + ((size_t)g << 10) + dg;
  uint16_t xA0 = xa0p[0], xA1 = xa0p[NG], xA2 = xa0p[2 * (size_t)NG], xA3 = xa0p[3 * (size_t)NG];
  uint16_t xB0 = 0, xB1 = 0, xB2 = 0, xB3 = 0;

#pragma unroll 1
  for (int t = t0; t < t0 + CHUNK; ++t) {
    // ================= phase A(t) =================
    f32x4 a0 = {0,0,0,0}, a1 = {0,0,0,0}, a2 = {0,0,0,0}, a3 = {0,0,0,0};
    if (t > 0) do_mfma(lHA, a0, a1, a2, a3);
    if (t > 0) { ++token; do_stage(grpB, t - 1, lHB, token); }   // overlap with MFMA retire
    {
      const uint16_t* xb = XP + (((size_t)(t - t0) * NB) + bB0) * NG + ((size_t)g << 10) + dg;
      xB0 = xb[0]; xB1 = xb[NG]; xB2 = xb[2 * (size_t)NG]; xB3 = xb[3 * (size_t)NG];
    }
    do_gates(a0, a1, a2, a3, xA0, xA1, xA2, xA3, cA, bA0, t);
    __syncthreads();   // drains lHB gloads + A publish stores
    if (tid == 0)
      __hip_atomic_store(flags + ((((size_t)t * 4 + grpA) << 5) + g_d) * 4, 1u,
                         __ATOMIC_RELAXED, __HIP_MEMORY_SCOPE_AGENT);

    // ================= phase B(t) =================
    f32x4 e0 = {0,0,0,0}, e1 = {0,0,0,0}, e2 = {0,0,0,0}, e3 = {0,0,0,0};
    if (t > 0) do_mfma(lHB, e0, e1, e2, e3);
    if (t + 1 < t0 + CHUNK) { ++token; do_stage(grpA, t, lHA, token); }
    {
      int tn = (t + 1 < t0 + CHUNK) ? (t + 1) : t;
      const uint16_t* xa = XP + (((size_t)(tn - t0) * NB) + bA0) * NG + ((size_t)g << 10) + dg;
      xA0 = xa[0]; xA1 = xa[NG]; xA2 = xa[2 * (size_t)NG]; xA3 = xa[3 * (size_t)NG];
    }
    do_gates(e0, e1, e2, e3, xB0, xB1, xB2, xB3, cB, bB0, t);
    __syncthreads();   // drains lHA gloads + B publish stores
    if (tid == 0)
      __hip_atomic_store(flags + ((((size_t)t * 4 + grpB) << 5) + g_d) * 4, 1u,
                         __ATOMIC_RELAXED, __HIP_MEMORY_SCOPE_AGENT);
  }

  float csA = (g == 0) ? cA[0] : (g == 1) ? cA[1] : (g == 2) ? cA[2] : cA[3];
  cbuf[(size_t)(bA0 + g) * ND + dg] = csA;
  float csB = (g == 0) ? cB[0] : (g == 1) ? cB[1] : (g == 2) ? cB[2] : cB[3];
  cbuf[(size_t)(bB0 + g) * ND + dg] = csB;
}

// ---------------- launch ----------------
extern "C" void kernel_launch(void* const* d_in, const int* in_sizes, int n_in,
                              void* d_out, int out_size, void* d_ws, size_t ws_size,
                              hipStream_t stream) {
  const float* emb = (const float*)d_in[0];
  const float* W_ii = (const float*)d_in[1];
  const float* b_ii = (const float*)d_in[2];
  const float* W_if = (const float*)d_in[3];
  const float* b_if = (const float*)d_in[4];
  const float* W_ig = (const float*)d_in[5];
  const float* b_ig = (const float*)d_in[6];
  const float* W_io = (const float*)d_in[7];
  const float* b_io = (const float*)d_in[8];
  const float* W_hi = (const float*)d_in[9];
  const float* W_hf = (const float*)d_in[10];
  const float* W_hg = (const float*)d_in[11];
  const float* W_ho = (const float*)d_in[12];

  char* ws = (char*)d_ws;
  uint16_t* hring = (uint16_t*)ws;                       // 134217728 B [B][S][D]
  uint16_t* wx    = (uint16_t*)(ws + 134217728);         // 8388608 B
  uint16_t* wh    = (uint16_t*)(ws + 142606336);         // 8388608 B
  uint16_t* xpA   = (uint16_t*)(ws + 150994944);         // 67108864 B
  uint16_t* xpB   = (uint16_t*)(ws + 218103808);         // 67108864 B
  float*    cbuf  = (float*)(ws + 285212672);            // 262144 B
  uint32_t* flags = (uint32_t*)(ws + 285474816);         // 2097152 B [NS][4][32] x16B

  hipMemsetAsync(flags, 0, 2097152, stream);

  k_cvt<<<256, 256, 0, stream>>>(W_ii, wx + 0 * 1048576, 262144);
  k_cvt<<<256, 256, 0, stream>>>(W_if, wx + 1 * 1048576, 262144);
  k_cvt<<<256, 256, 0, stream>>>(W_ig, wx + 2 * 1048576, 262144);
  k_cvt<<<256, 256, 0, stream>>>(W_io, wx + 3 * 1048576, 262144);
  k_cvt<<<256, 256, 0, stream>>>(W_hi, wh + 0 * 1048576, 262144);
  k_cvt<<<256, 256, 0, stream>>>(W_hf, wh + 1 * 1048576, 262144);
  k_cvt<<<256, 256, 0, stream>>>(W_hg, wh + 2 * 1048576, 262144);
  k_cvt<<<256, 256, 0, stream>>>(W_ho, wh + 3 * 1048576, 262144);

  // prologue: all 256 WGs compute x_proj for chunk 0
  k_fused<<<256, 512, 0, stream>>>(emb, wx, wh, xpA, xpB, b_ii, b_if, b_ig, b_io,
                                   hring, cbuf, flags, (float*)d_out, -1);
  for (int chk = 0; chk < NCHUNK; ++chk)
    k_fused<<<256, 512, 0, stream>>>(emb, wx, wh, xpA, xpB, b_ii, b_if, b_ig, b_io,
                                     hring, cbuf, flags, (float*)d_out, chk);
}